// Round 12
// baseline (594.308 us; speedup 1.0000x reference)
//
#include <hip/hip_runtime.h>
#include <math.h>

#define EDIM 768
#define E3 2304

typedef __attribute__((ext_vector_type(8))) short short8;
typedef __attribute__((ext_vector_type(8))) unsigned short ushort8;
typedef __attribute__((ext_vector_type(4))) float f32x4;

__device__ inline void gload_lds16(const void* g, void* l) {
  __builtin_amdgcn_global_load_lds((const __attribute__((address_space(1))) void*)g,
                                   (__attribute__((address_space(3))) void*)l, 16, 0, 0);
}

__device__ inline unsigned short f2b_rne(float f) {
  unsigned int u = __builtin_bit_cast(unsigned int, f);
  u = (u + 0x7fffu + ((u >> 16) & 1u)) >> 16;
  return (unsigned short)u;
}
__device__ inline float b2f(unsigned short u) {
  unsigned int x = ((unsigned int)u) << 16;
  return __builtin_bit_cast(float, x);
}
__device__ inline float ldv(float v) { return v; }
__device__ inline float ldv(unsigned short v) { return b2f(v); }

// ---------------- fp32 -> bf16 conversion ----------------
__global__ __launch_bounds__(256) void f2bf(const float* __restrict__ in,
                                            unsigned short* __restrict__ out, size_t n) {
  size_t i = ((size_t)blockIdx.x * blockDim.x + threadIdx.x) * 8;
  size_t stride = (size_t)gridDim.x * blockDim.x * 8;
  for (; i < n; i += stride) {
    float4 a = *(const float4*)(in + i);
    float4 b = *(const float4*)(in + i + 4);
    ushort8 o;
    o[0] = f2b_rne(a.x); o[1] = f2b_rne(a.y); o[2] = f2b_rne(a.z); o[3] = f2b_rne(a.w);
    o[4] = f2b_rne(b.x); o[5] = f2b_rne(b.y); o[6] = f2b_rne(b.z); o[7] = f2b_rne(b.w);
    *(ushort8*)(out + i) = o;
  }
}

// three conversions in one launch (weights)
__global__ __launch_bounds__(256) void f2bf3(
    const float* __restrict__ i0, unsigned short* __restrict__ o0, size_t n0,
    const float* __restrict__ i1, unsigned short* __restrict__ o1, size_t n1,
    const float* __restrict__ i2, unsigned short* __restrict__ o2, size_t n2) {
  size_t c8 = (size_t)blockIdx.x * blockDim.x + threadIdx.x;
  size_t stride = (size_t)gridDim.x * blockDim.x;
  size_t t0 = n0 >> 3, t1 = t0 + (n1 >> 3), t2 = t1 + (n2 >> 3);
  for (; c8 < t2; c8 += stride) {
    const float* src; unsigned short* dst; size_t i;
    if (c8 < t0) { src = i0; dst = o0; i = c8 * 8; }
    else if (c8 < t1) { src = i1; dst = o1; i = (c8 - t0) * 8; }
    else { src = i2; dst = o2; i = (c8 - t1) * 8; }
    float4 a = *(const float4*)(src + i);
    float4 b = *(const float4*)(src + i + 4);
    ushort8 o;
    o[0] = f2b_rne(a.x); o[1] = f2b_rne(a.y); o[2] = f2b_rne(a.z); o[3] = f2b_rne(a.w);
    o[4] = f2b_rne(b.x); o[5] = f2b_rne(b.y); o[6] = f2b_rne(b.z); o[7] = f2b_rne(b.w);
    *(ushort8*)(dst + i) = o;
  }
}

// ---------------- mask statistics (single launch, 1024 threads) ----------------
__global__ __launch_bounds__(1024) void mask_stats(
    const int* __restrict__ am, float* __restrict__ wsum, float* __restrict__ svalid,
    float* __restrict__ cnt2, float* __restrict__ secv, float* __restrict__ cnt3) {
  int tid = threadIdx.x;
  int s = 0;
  const int* p = am + (size_t)tid * 64;
  for (int w = 0; w < 64; ++w) s += p[w];
  wsum[tid] = (float)s;
  float sv = s > 0 ? 1.f : 0.f;
  svalid[tid] = sv;
  __shared__ float sva[1024];
  sva[tid] = sv;
  __syncthreads();
  if (tid < 64) {
    float c = 0.f;
    for (int u = 0; u < 16; ++u) c += sva[tid * 16 + u];
    cnt2[tid] = c;
    secv[tid] = c > 0.f ? 1.f : 0.f;
  }
  __syncthreads();
  if (tid < 64) sva[tid] = secv[tid];
  __syncthreads();
  if (tid < 8) {
    float c = 0.f;
    for (int s2 = 0; s2 < 8; ++s2) c += sva[tid * 8 + s2];
    cnt3[tid] = c;
  }
}

// ---------------- Q,K projection: BK=64 double-buffered bf16 MFMA GEMM ----------
// (R8-proven inner loop: ~175 us, MfmaUtil ~39%, 0 bank conflicts.)
// 256x256 tile, BK=64, 8 waves (2Mx4N, per-wave 128x64), 2 LDS slots (128 KiB).
// Output in HEAD-BLOCKED layout for coalesced attention reads:
//   qk_blk[sent][head][q|k][kc(6)][row 64][col 32] bf16
__global__ __launch_bounds__(512, 2) void gemm8(
    const unsigned short* __restrict__ A, const unsigned short* __restrict__ B,
    const float* __restrict__ bias, unsigned short* __restrict__ C,
    int M, int N, int K) {
  __shared__ unsigned short lds[2][32768];  // [slot][A:256x64 | B:256x64]
  const int tid = threadIdx.x;
  const int w = tid >> 6;
  const int lane = tid & 63;
  const int nbx = N / 256;
  const int cpx = gridDim.x >> 3;
  const int bid = blockIdx.x;
  const int swz = (bid & 7) * cpx + (bid >> 3);
  const int m0 = (swz / nbx) * 256;
  const int n0 = (swz % nbx) * 256;
  const int wr = w >> 2, wc = w & 3;  // 2x4 wave grid; per-wave C: 128x64
  const int fr = lane & 15;
  const int g = lane >> 4;
  const int NT64 = K / 64;
  f32x4 acc[8][4] = {};

  // staging source coords: chunk S -> row = S>>3, colchunk = (S&7)^(row&7)
  int srow[4], scol[4];
#pragma unroll
  for (int q = 0; q < 4; ++q) {
    int S = q * 512 + tid;
    srow[q] = S >> 3;
    scol[q] = ((S & 7) ^ (srow[q] & 7)) * 8;
  }
  auto stageA = [&](int t, int slot) {
    const int kt = t * 64;
#pragma unroll
    for (int q = 0; q < 4; ++q)
      gload_lds16(A + (size_t)(m0 + srow[q]) * K + kt + scol[q],
                  &lds[slot][(q * 512 + w * 64) * 8]);
  };
  auto stageB = [&](int t, int slot) {
    const int kt = t * 64;
#pragma unroll
    for (int q = 0; q < 4; ++q)
      gload_lds16(B + (size_t)(n0 + srow[q]) * K + kt + scol[q],
                  &lds[slot][16384 + (q * 512 + w * 64) * 8]);
  };
  // fragment read offsets (ushort units), chunk-in-row = ks*4+g, XOR row&7
  int aoff[2][8], boff[2][4];
#pragma unroll
  for (int ks = 0; ks < 2; ++ks) {
#pragma unroll
    for (int i = 0; i < 8; ++i) {
      int r = wr * 128 + i * 16 + fr;
      aoff[ks][i] = (r * 8 + ((ks * 4 + g) ^ (r & 7))) * 8;
    }
#pragma unroll
    for (int j = 0; j < 4; ++j) {
      int r = wc * 64 + j * 16 + fr;
      boff[ks][j] = 16384 + (r * 8 + ((ks * 4 + g) ^ (r & 7))) * 8;
    }
  }

  // prologue: stage tile 0 into slot 0, drain, barrier
  stageA(0, 0);
  stageB(0, 0);
  asm volatile("s_waitcnt vmcnt(0)" ::: "memory");
  __builtin_amdgcn_sched_barrier(0);
  __builtin_amdgcn_s_barrier();
  __builtin_amdgcn_sched_barrier(0);

  int slot = 0;
  for (int t = 0; t < NT64; ++t) {
    const unsigned short* ls = lds[slot];
    if (t + 1 < NT64) stageA(t + 1, slot ^ 1);  // issue early (hide under ks0)
    short8 av[8], bv[4];
    // ---- ks = 0 cluster
#pragma unroll
    for (int i = 0; i < 8; ++i) av[i] = *(const short8*)(ls + aoff[0][i]);
#pragma unroll
    for (int j = 0; j < 4; ++j) bv[j] = *(const short8*)(ls + boff[0][j]);
    __builtin_amdgcn_s_setprio(1);
#pragma unroll
    for (int i = 0; i < 8; ++i)
#pragma unroll
      for (int j = 0; j < 4; ++j)
        acc[i][j] = __builtin_amdgcn_mfma_f32_16x16x32_bf16(av[i], bv[j], acc[i][j], 0, 0, 0);
    __builtin_amdgcn_s_setprio(0);
    if (t + 1 < NT64) stageB(t + 1, slot ^ 1);  // issue mid-tile
    // ---- ks = 1 cluster
#pragma unroll
    for (int i = 0; i < 8; ++i) av[i] = *(const short8*)(ls + aoff[1][i]);
#pragma unroll
    for (int j = 0; j < 4; ++j) bv[j] = *(const short8*)(ls + boff[1][j]);
    __builtin_amdgcn_s_setprio(1);
#pragma unroll
    for (int i = 0; i < 8; ++i)
#pragma unroll
      for (int j = 0; j < 4; ++j)
        acc[i][j] = __builtin_amdgcn_mfma_f32_16x16x32_bf16(av[i], bv[j], acc[i][j], 0, 0, 0);
    __builtin_amdgcn_s_setprio(0);
    // boundary: tile t+1 must be fully landed before next iteration reads it
    asm volatile("s_waitcnt vmcnt(0)" ::: "memory");
    __builtin_amdgcn_sched_barrier(0);
    __builtin_amdgcn_s_barrier();
    __builtin_amdgcn_sched_barrier(0);
    slot ^= 1;
  }

  // epilogue: bias + bf16 store into head-blocked layout.
  const int cl = lane & 15;
  const int rg = (lane >> 4) * 4;
#pragma unroll
  for (int i = 0; i < 8; ++i) {
    const int mrow0 = m0 + wr * 128 + i * 16 + rg;
#pragma unroll
    for (int j = 0; j < 4; ++j) {
      const int col = n0 + wc * 64 + j * 16 + cl;
      const float bvv = bias[col];
      const int qkf = col >= 768;
      const int within = col - qkf * 768;
      const int hh = within / 192;
      const int rem = within - hh * 192;
      const int kc = rem >> 5;
      const int cw = rem & 31;
#pragma unroll
      for (int r = 0; r < 4; ++r) {
        const int m = mrow0 + r;
        const int sent = m >> 6;
        const int row = m & 63;
        const size_t addr =
            ((((size_t)sent * 4 + hh) * 2 + qkf) * 6 + kc) * 2048 + row * 32 + cw;
        C[addr] = f2b_rne(acc[i][j][r] + bvv);
      }
    }
  }
}

// ---------------- word-level attention from head-blocked Q,K (bf16) ----------------
// qk_blk[sent][head][q|k][kc][64][32]: coalesced fragment loads. Pooling loop
// restructured for ILP: 8 rows/group, 24 hoisted loads before the FMA block.
__global__ __launch_bounds__(256) void attn_qk(
    const unsigned short* __restrict__ qk, const unsigned short* __restrict__ xbf,
    const int* __restrict__ am, const float* __restrict__ wsum,
    unsigned short* __restrict__ xbarbf) {
  __shared__ float abar_all[4][64];
  __shared__ float msk[64];
  const int n = blockIdx.x;
  const int tid = threadIdx.x;
  const int h = tid >> 6;  // wave = head
  const int lane = tid & 63;
  if (tid < 64) msk[tid] = (am[(size_t)n * 64 + tid] > 0) ? 1.f : 0.f;
  __syncthreads();
  const int fr = lane & 15;
  const int fk = (lane >> 4) * 8;
  const unsigned short* Sg = qk + (size_t)n * 98304 + (size_t)h * 24576;  // head base
  const unsigned short* Kb = Sg + 12288;                                   // k half
  f32x4 acc[4][4] = {};
#pragma unroll
  for (int ks = 0; ks < 6; ++ks) {
    short8 aq[4], bk[4];
#pragma unroll
    for (int i = 0; i < 4; ++i)
      aq[i] = *(const short8*)(Sg + ks * 2048 + (i * 16 + fr) * 32 + fk);
#pragma unroll
    for (int j = 0; j < 4; ++j)
      bk[j] = *(const short8*)(Kb + ks * 2048 + (j * 16 + fr) * 32 + fk);
#pragma unroll
    for (int i = 0; i < 4; ++i)
#pragma unroll
      for (int j = 0; j < 4; ++j)
        acc[i][j] = __builtin_amdgcn_mfma_f32_16x16x32_bf16(aq[i], bk[j], acc[i][j], 0, 0, 0);
  }
  const float den = wsum[n] + 1e-10f;
  const float scale = 0.07216878364870323f;  // 1/sqrt(192)
  float mcol[4];
#pragma unroll
  for (int j = 0; j < 4; ++j) mcol[j] = msk[j * 16 + fr];
  float colsum[4] = {0.f, 0.f, 0.f, 0.f};
#pragma unroll
  for (int i = 0; i < 4; ++i) {
#pragma unroll
    for (int r = 0; r < 4; ++r) {
      float s[4];
      float mx = -1e30f;
#pragma unroll
      for (int j = 0; j < 4; ++j) {
        float v = mcol[j] > 0.f ? acc[i][j][r] * scale : -1e9f;
        s[j] = v;
        mx = fmaxf(mx, v);
      }
      mx = fmaxf(mx, __shfl_xor(mx, 1));
      mx = fmaxf(mx, __shfl_xor(mx, 2));
      mx = fmaxf(mx, __shfl_xor(mx, 4));
      mx = fmaxf(mx, __shfl_xor(mx, 8));
      float sum = 0.f;
#pragma unroll
      for (int j = 0; j < 4; ++j) { s[j] = expf(s[j] - mx); sum += s[j]; }
      sum += __shfl_xor(sum, 1);
      sum += __shfl_xor(sum, 2);
      sum += __shfl_xor(sum, 4);
      sum += __shfl_xor(sum, 8);
      float wrow = msk[i * 16 + (lane >> 4) * 4 + r] / den;
      float f = wrow / sum;
#pragma unroll
      for (int j = 0; j < 4; ++j) colsum[j] += s[j] * f;
    }
  }
#pragma unroll
  for (int j = 0; j < 4; ++j) {
    float cs = colsum[j];
    cs += __shfl_xor(cs, 16);
    cs += __shfl_xor(cs, 32);
    if (lane < 16) abar_all[h][j * 16 + lane] = cs;
  }
  __syncthreads();
  // pooling: xbar[h][d] = sum_m abar[h][m] * X[m][d].
  // 8 rows per group; all 24 X-loads hoisted/issued before the FMA block (ILP).
  const unsigned short* xg = xbf + (size_t)n * 64 * 768;
  float a4[4][3] = {};
#pragma unroll 2
  for (int mg = 0; mg < 64; mg += 8) {
    float xv[8][3];
#pragma unroll
    for (int r = 0; r < 8; ++r)
#pragma unroll
      for (int u = 0; u < 3; ++u)
        xv[r][u] = b2f(xg[(size_t)(mg + r) * 768 + u * 256 + tid]);
#pragma unroll
    for (int r = 0; r < 8; ++r) {
      float ab0 = abar_all[0][mg + r], ab1 = abar_all[1][mg + r];
      float ab2 = abar_all[2][mg + r], ab3 = abar_all[3][mg + r];
#pragma unroll
      for (int u = 0; u < 3; ++u) {
        a4[0][u] += ab0 * xv[r][u];
        a4[1][u] += ab1 * xv[r][u];
        a4[2][u] += ab2 * xv[r][u];
        a4[3][u] += ab3 * xv[r][u];
      }
    }
  }
#pragma unroll
  for (int hh = 0; hh < 4; ++hh)
#pragma unroll
    for (int u = 0; u < 3; ++u)
      xbarbf[((size_t)hh * 1024 + n) * 768 + u * 256 + tid] = f2b_rne(a4[hh][u]);
}

// ---------------- bf16 MFMA GEMM, 128x64 tile, grid.z-batched, fp32/bf16 out ------
__global__ __launch_bounds__(256) void gemm_bf16_64(
    const unsigned short* __restrict__ A, const unsigned short* __restrict__ B,
    const float* __restrict__ bias, const float* __restrict__ cnt,
    float* __restrict__ C, unsigned short* __restrict__ Cb,
    int K, int ldc, size_t Az, size_t Bz, int colz) {
  __shared__ unsigned short smA[128 * 32];
  __shared__ unsigned short smB[64 * 32];
  const int tid = threadIdx.x;
  const int wid = tid >> 6;
  const int lane = tid & 63;
  const int za = blockIdx.z;
  A += (size_t)za * Az;
  B += (size_t)za * Bz;
  const int m0 = blockIdx.y * 128;
  const int nb = blockIdx.x * 64;
  const int wr = wid >> 1, wc = wid & 1;
  const int srow = lane >> 2;
  const int scol = (lane & 3) * 8;
  const int fr = lane & 15;
  const int fk = (lane >> 4) * 8;
  f32x4 acc[4][2] = {};
  for (int k0 = 0; k0 < K; k0 += 32) {
#pragma unroll
    for (int t = 0; t < 2; ++t) {
      const int r0 = wid * 32 + t * 16;
      gload_lds16(A + (size_t)(m0 + r0 + srow) * K + k0 + scol, &smA[r0 * 32]);
    }
    gload_lds16(B + (size_t)(nb + wid * 16 + srow) * K + k0 + scol, &smB[wid * 16 * 32]);
    __syncthreads();
    short8 af[4], bfr[2];
#pragma unroll
    for (int i = 0; i < 4; ++i)
      af[i] = *(const short8*)&smA[(wr * 64 + i * 16 + fr) * 32 + fk];
#pragma unroll
    for (int j = 0; j < 2; ++j)
      bfr[j] = *(const short8*)&smB[(wc * 32 + j * 16 + fr) * 32 + fk];
#pragma unroll
    for (int i = 0; i < 4; ++i)
#pragma unroll
      for (int j = 0; j < 2; ++j)
        acc[i][j] = __builtin_amdgcn_mfma_f32_16x16x32_bf16(af[i], bfr[j], acc[i][j], 0, 0, 0);
    __syncthreads();
  }
  const int cl = lane & 15;
  const int rg = (lane >> 4) * 4;
#pragma unroll
  for (int i = 0; i < 4; ++i) {
    const int mrow0 = m0 + wr * 64 + i * 16 + rg;
#pragma unroll
    for (int j = 0; j < 2; ++j) {
      const int gc = za * colz + nb + wc * 32 + j * 16 + cl;
      const float bv = bias[gc];
#pragma unroll
      for (int r = 0; r < 4; ++r) {
        const int m = mrow0 + r;
        float sf = 1.f;
        if (cnt) { float c = cnt[m]; sf = c / (c + 1e-10f); }
        float v = acc[i][j][r] + bv * sf;
        if (Cb) Cb[(size_t)m * ldc + gc] = f2b_rne(v);
        else C[(size_t)m * ldc + gc] = v;
      }
    }
  }
}

// ---------------- fp32 GEMM: out[m,n] = sum_k X[m*lda+k]*W[n,k] + bias[n]*sfac(m) ------
#define BM 64
#define BN 64
#define BK 16
__global__ __launch_bounds__(256) void gemm_nt(
    const float* __restrict__ X, const float* __restrict__ W,
    const float* __restrict__ bias, const float* __restrict__ cnt,
    float* __restrict__ out, int M, int N, int K, int lda, int ldc) {
  __shared__ float As[BK][BM + 4];
  __shared__ float Bs[BK][BN + 4];
  const int tid = threadIdx.x;
  const int m0 = blockIdx.y * BM;
  const int n0 = blockIdx.x * BN;
  const int tx = tid & 15, ty = tid >> 4;
  const int lr = tid >> 2;
  const int lc = (tid & 3) * 4;
  float acc[4][4];
#pragma unroll
  for (int i = 0; i < 4; ++i)
#pragma unroll
    for (int j = 0; j < 4; ++j) acc[i][j] = 0.f;
  for (int k0 = 0; k0 < K; k0 += BK) {
    float4 xa = make_float4(0.f, 0.f, 0.f, 0.f);
    if (m0 + lr < M) xa = *(const float4*)(X + (size_t)(m0 + lr) * lda + k0 + lc);
    float4 wb = *(const float4*)(W + (size_t)(n0 + lr) * K + k0 + lc);
    As[lc + 0][lr] = xa.x; As[lc + 1][lr] = xa.y; As[lc + 2][lr] = xa.z; As[lc + 3][lr] = xa.w;
    Bs[lc + 0][lr] = wb.x; Bs[lc + 1][lr] = wb.y; Bs[lc + 2][lr] = wb.z; Bs[lc + 3][lr] = wb.w;
    __syncthreads();
#pragma unroll
    for (int kk = 0; kk < BK; ++kk) {
      float4 av = *(const float4*)&As[kk][ty * 4];
      float4 bv = *(const float4*)&Bs[kk][tx * 4];
      float a4[4] = {av.x, av.y, av.z, av.w};
      float b4[4] = {bv.x, bv.y, bv.z, bv.w};
#pragma unroll
      for (int i = 0; i < 4; ++i)
#pragma unroll
        for (int j = 0; j < 4; ++j) acc[i][j] += a4[i] * b4[j];
    }
    __syncthreads();
  }
#pragma unroll
  for (int i = 0; i < 4; ++i) {
    int m = m0 + ty * 4 + i;
    if (m < M) {
      float sf = 1.f;
      if (cnt) { float c = cnt[m]; sf = c / (c + 1e-10f); }
      float4 o;
      o.x = acc[i][0] + bias[n0 + tx * 4 + 0] * sf;
      o.y = acc[i][1] + bias[n0 + tx * 4 + 1] * sf;
      o.z = acc[i][2] + bias[n0 + tx * 4 + 2] * sf;
      o.w = acc[i][3] + bias[n0 + tx * 4 + 3] * sf;
      *(float4*)(out + (size_t)m * ldc + n0 + tx * 4) = o;
    }
  }
}

// ---------------- small attention (L=16 or 8), pooled output, fp32 or bf16 qkv ----
template <class T>
__global__ __launch_bounds__(256) void small_attn(
    const T* __restrict__ qkv, const float* __restrict__ maskv,
    const float* __restrict__ cnt, float* __restrict__ obar, int L) {
  const int n = blockIdx.x;
  const int h = blockIdx.y;
  const int tid = threadIdx.x;
  __shared__ float red[16][17];
  __shared__ float abar[16];
  const T* qb = qkv + (size_t)n * L * E3 + h * 192;
  const T* kb = qb + EDIM;
  const T* vb = qb + 2 * EDIM;
  const float scale = 0.07216878364870323f;
  if (tid < L * L) {
    int l = tid / L, m = tid % L;
    float s = 0.f;
    for (int dd = 0; dd < 192; ++dd) s += ldv(qb[(size_t)l * E3 + dd]) * ldv(kb[(size_t)m * E3 + dd]);
    s = (maskv[n * L + m] > 0.f) ? s * scale : -1e9f;
    float mx = s;
    for (int off = L >> 1; off > 0; off >>= 1) mx = fmaxf(mx, __shfl_xor(mx, off));
    float p = expf(s - mx);
    float sum = p;
    for (int off = L >> 1; off > 0; off >>= 1) sum += __shfl_xor(sum, off);
    float dn = cnt[n] + 1e-10f;
    float wl = (maskv[n * L + l] > 0.f) ? (1.f / dn) : 0.f;
    red[l][m] = p / sum * wl;
  }
  __syncthreads();
  if (tid < L) {
    float s = 0.f;
    for (int l2 = 0; l2 < L; ++l2) s += red[l2][tid];
    abar[tid] = s;
  }
  __syncthreads();
  if (tid < 192) {
    float acc = 0.f;
    for (int m = 0; m < L; ++m) acc += abar[m] * ldv(vb[(size_t)m * E3 + tid]);
    obar[(size_t)n * EDIM + h * 192 + tid] = acc;
  }
}

// ---------------- fusion head: [8,768] doc -> [8,3] ----------------
__global__ __launch_bounds__(256) void head_kernel(
    const float* __restrict__ doc, const float* __restrict__ hand,
    const float* __restrict__ bp_w, const float* __restrict__ bp_b,
    const float* __restrict__ hp_w, const float* __restrict__ hp_b,
    const float* __restrict__ gate_w, const float* __restrict__ gate_b,
    const float* __restrict__ fg, const float* __restrict__ fbv,
    const float* __restrict__ fc1_w, const float* __restrict__ fc1_b,
    const float* __restrict__ g1, const float* __restrict__ b1,
    const float* __restrict__ fc2_w, const float* __restrict__ fc2_b,
    float* __restrict__ out) {
  int b = blockIdx.x, tid = threadIdx.x;
  __shared__ float bp[256], hp[256], fz[256], hz[128];
  const float* dr = doc + (size_t)b * 768;
  float acc = bp_b[tid];
  for (int k = 0; k < 768; ++k) acc += dr[k] * bp_w[(size_t)tid * 768 + k];
  bp[tid] = acc;
  const float* hr = hand + b * 20;
  float acc2 = hp_b[tid];
  for (int k = 0; k < 20; ++k) acc2 += hr[k] * hp_w[tid * 20 + k];
  hp[tid] = acc2;
  __syncthreads();
  float g = gate_b[tid];
  for (int k = 0; k < 256; ++k) g += bp[k] * gate_w[tid * 512 + k];
  for (int k = 0; k < 256; ++k) g += hp[k] * gate_w[tid * 512 + 256 + k];
  g = 1.f / (1.f + expf(-g));
  float fu = g * bp[tid] + (1.f - g) * hp[tid];
  fz[tid] = fu;
  __syncthreads();
  float mu = 0.f;
  for (int k = 0; k < 256; ++k) mu += fz[k];
  mu /= 256.f;
  float va = 0.f;
  for (int k = 0; k < 256; ++k) { float d = fz[k] - mu; va += d * d; }
  va /= 256.f;
  float fl = (fu - mu) / sqrtf(va + 1e-5f) * fg[tid] + fbv[tid];
  __syncthreads();
  fz[tid] = fl;
  __syncthreads();
  if (tid < 128) {
    float a = fc1_b[tid];
    for (int k = 0; k < 256; ++k) a += fz[k] * fc1_w[tid * 256 + k];
    hz[tid] = fmaxf(a, 0.f);
  }
  __syncthreads();
  float mu2 = 0.f;
  for (int k = 0; k < 128; ++k) mu2 += hz[k];
  mu2 /= 128.f;
  float va2 = 0.f;
  for (int k = 0; k < 128; ++k) { float d = hz[k] - mu2; va2 += d * d; }
  va2 /= 128.f;
  __syncthreads();
  if (tid < 128) hz[tid] = (hz[tid] - mu2) / sqrtf(va2 + 1e-5f) * g1[tid] + b1[tid];
  __syncthreads();
  if (tid < 3) {
    float o = fc2_b[tid];
    for (int k = 0; k < 128; ++k) o += hz[k] * fc2_w[tid * 128 + k];
    out[b * 3 + tid] = o;
  }
}

extern "C" void kernel_launch(void* const* d_in, const int* in_sizes, int n_in,
                              void* d_out, int out_size, void* d_ws, size_t ws_size,
                              hipStream_t stream) {
  const float* we      = (const float*)d_in[0];
  const int*   am      = (const int*)d_in[1];
  const float* hand    = (const float*)d_in[2];
  const float* w_w_in  = (const float*)d_in[3];
  const float* w_b_in  = (const float*)d_in[4];
  const float* w_w_out = (const float*)d_in[5];
  const float* w_b_out = (const float*)d_in[6];
  const float* s_w_in  = (const float*)d_in[7];
  const float* s_b_in  = (const float*)d_in[8];
  const float* s_w_out = (const float*)d_in[9];
  const float* s_b_out = (const float*)d_in[10];
  const float* c_w_in  = (const float*)d_in[11];
  const float* c_b_in  = (const float*)d_in[12];
  const float* c_w_out = (const float*)d_in[13];
  const float* c_b_out = (const float*)d_in[14];
  const float* bp_w = (const float*)d_in[15];
  const float* bp_b = (const float*)d_in[16];
  const float* hp_w = (const float*)d_in[17];
  const float* hp_b = (const float*)d_in[18];
  // d_in[19..22] = fa_* (cross-attention) — output unused by the reference, skipped.
  const float* gate_w = (const float*)d_in[23];
  const float* gate_b = (const float*)d_in[24];
  const float* fus_g  = (const float*)d_in[25];
  const float* fus_b  = (const float*)d_in[26];
  const float* fc1_w  = (const float*)d_in[27];
  const float* fc1_b  = (const float*)d_in[28];
  const float* ln1_g  = (const float*)d_in[29];
  const float* ln1_b  = (const float*)d_in[30];
  const float* fc2_w  = (const float*)d_in[31];
  const float* fc2_b  = (const float*)d_in[32];
  float* out = (float*)d_out;

  // big buffers at the bottom of the workspace
  unsigned short* qk  = (unsigned short*)d_ws;                      // head-blocked, 201 MB
  unsigned short* xbf = qk + (size_t)65536 * 1536;                  // [65536][768]  bf16

  // small buffers carved from the top
  char* end = (char*)d_ws + ws_size;
  auto carveb = [&](size_t bytes) {
    size_t b = (bytes + 255) & ~(size_t)255;
    end -= b;
    return (void*)end;
  };
  unsigned short* xbarbf  = (unsigned short*)carveb((size_t)4 * 1024 * 768 * 2);
  unsigned short* obarbf  = (unsigned short*)carveb((size_t)1024 * 768 * 2);
  unsigned short* sentbf  = (unsigned short*)carveb((size_t)1024 * 768 * 2);
  unsigned short* qkv2bf  = (unsigned short*)carveb((size_t)1024 * 2304 * 2);
  float* obar2  = (float*)carveb(64 * 768 * 4);
  float* sec    = (float*)carveb(64 * 768 * 4);
  float* qkv3   = (float*)carveb(64 * 2304 * 4);
  float* obar3  = (float*)carveb(8 * 768 * 4);
  float* doc    = (float*)carveb(8 * 768 * 4);
  float* wsum   = (float*)carveb(1024 * 4);
  float* svalid = (float*)carveb(1024 * 4);
  float* cnt2   = (float*)carveb(64 * 4);
  float* secv   = (float*)carveb(64 * 4);
  float* cnt3   = (float*)carveb(8 * 4);
  unsigned short* wbf_in = (unsigned short*)carveb((size_t)2304 * 768 * 2);
  unsigned short* wobf   = (unsigned short*)carveb((size_t)768 * 768 * 2);
  unsigned short* wsbf   = (unsigned short*)carveb((size_t)2304 * 768 * 2);

  // prep: weights -> bf16 (single launch), mask stats (single launch)
  f2bf3<<<2048, 256, 0, stream>>>(w_w_in, wbf_in, (size_t)2304 * 768,
                                  w_w_out, wobf, (size_t)768 * 768,
                                  s_w_in, wsbf, (size_t)2304 * 768);
  mask_stats<<<1, 1024, 0, stream>>>(am, wsum, svalid, cnt2, secv, cnt3);

  // word level
  f2bf<<<2048, 256, 0, stream>>>(we, xbf, (size_t)65536 * 768);
  gemm8<<<(65536 / 256) * (1536 / 256), 512, 0, stream>>>(xbf, wbf_in, w_b_in, qk,
                                                          65536, 1536, 768);
  attn_qk<<<1024, 256, 0, stream>>>(qk, xbf, am, wsum, xbarbf);
  // V-projection (batched per head): obar[n, h*192+c] = xbar[h][n,:] @ Wv_h^T + bv*sfac
  gemm_bf16_64<<<dim3(3, 8, 4), 256, 0, stream>>>(
      xbarbf, wbf_in + (size_t)1536 * 768, w_b_in + 1536, wsum, nullptr, obarbf,
      768, 768, (size_t)1024 * 768, (size_t)192 * 768, 192);
  // sent = obar @ w_out^T + b_out * sfac
  gemm_bf16_64<<<dim3(12, 8, 1), 256, 0, stream>>>(
      obarbf, wobf, w_b_out, wsum, nullptr, sentbf, 768, 768, 0, 0, 0);
  // sentence level QKV
  gemm_bf16_64<<<dim3(36, 8, 1), 256, 0, stream>>>(
      sentbf, wsbf, s_b_in, nullptr, nullptr, qkv2bf, 768, 2304, 0, 0, 0);
  small_attn<<<dim3(64, 4), 256, 0, stream>>>(qkv2bf, svalid, cnt2, obar2, 16);
  gemm_nt<<<dim3(12, 1), 256, 0, stream>>>(obar2, s_w_out, s_b_out, cnt2, sec,
                                           64, 768, 768, 768, 768);
  // section level
  gemm_nt<<<dim3(36, 1), 256, 0, stream>>>(sec, c_w_in, c_b_in, nullptr, qkv3,
                                           64, 2304, 768, 768, 2304);
  small_attn<<<dim3(8, 4), 256, 0, stream>>>(qkv3, secv, cnt3, obar3, 8);
  gemm_nt<<<dim3(12, 1), 256, 0, stream>>>(obar3, c_w_out, c_b_out, cnt3, doc,
                                           8, 768, 768, 768, 768);
  // fusion head
  head_kernel<<<8, 256, 0, stream>>>(doc, hand, bp_w, bp_b, hp_w, hp_b, gate_w, gate_b,
                                     fus_g, fus_b, fc1_w, fc1_b, ln1_g, ln1_b, fc2_w, fc2_b, out);
}

// Round 13
// 578.209 us; speedup vs baseline: 1.0278x; 1.0278x over previous
//
#include <hip/hip_runtime.h>
#include <math.h>

#define EDIM 768
#define E3 2304

typedef __attribute__((ext_vector_type(8))) short short8;
typedef __attribute__((ext_vector_type(8))) unsigned short ushort8;
typedef __attribute__((ext_vector_type(4))) float f32x4;

__device__ inline void gload_lds16(const void* g, void* l) {
  __builtin_amdgcn_global_load_lds((const __attribute__((address_space(1))) void*)g,
                                   (__attribute__((address_space(3))) void*)l, 16, 0, 0);
}

__device__ inline unsigned short f2b_rne(float f) {
  unsigned int u = __builtin_bit_cast(unsigned int, f);
  u = (u + 0x7fffu + ((u >> 16) & 1u)) >> 16;
  return (unsigned short)u;
}
__device__ inline float b2f(unsigned short u) {
  unsigned int x = ((unsigned int)u) << 16;
  return __builtin_bit_cast(float, x);
}
__device__ inline float ldv(float v) { return v; }
__device__ inline float ldv(unsigned short v) { return b2f(v); }

// ---------------- fp32 -> bf16 conversion ----------------
__global__ __launch_bounds__(256) void f2bf(const float* __restrict__ in,
                                            unsigned short* __restrict__ out, size_t n) {
  size_t i = ((size_t)blockIdx.x * blockDim.x + threadIdx.x) * 8;
  size_t stride = (size_t)gridDim.x * blockDim.x * 8;
  for (; i < n; i += stride) {
    float4 a = *(const float4*)(in + i);
    float4 b = *(const float4*)(in + i + 4);
    ushort8 o;
    o[0] = f2b_rne(a.x); o[1] = f2b_rne(a.y); o[2] = f2b_rne(a.z); o[3] = f2b_rne(a.w);
    o[4] = f2b_rne(b.x); o[5] = f2b_rne(b.y); o[6] = f2b_rne(b.z); o[7] = f2b_rne(b.w);
    *(ushort8*)(out + i) = o;
  }
}

// three conversions in one launch (weights)
__global__ __launch_bounds__(256) void f2bf3(
    const float* __restrict__ i0, unsigned short* __restrict__ o0, size_t n0,
    const float* __restrict__ i1, unsigned short* __restrict__ o1, size_t n1,
    const float* __restrict__ i2, unsigned short* __restrict__ o2, size_t n2) {
  size_t c8 = (size_t)blockIdx.x * blockDim.x + threadIdx.x;
  size_t stride = (size_t)gridDim.x * blockDim.x;
  size_t t0 = n0 >> 3, t1 = t0 + (n1 >> 3), t2 = t1 + (n2 >> 3);
  for (; c8 < t2; c8 += stride) {
    const float* src; unsigned short* dst; size_t i;
    if (c8 < t0) { src = i0; dst = o0; i = c8 * 8; }
    else if (c8 < t1) { src = i1; dst = o1; i = (c8 - t0) * 8; }
    else { src = i2; dst = o2; i = (c8 - t1) * 8; }
    float4 a = *(const float4*)(src + i);
    float4 b = *(const float4*)(src + i + 4);
    ushort8 o;
    o[0] = f2b_rne(a.x); o[1] = f2b_rne(a.y); o[2] = f2b_rne(a.z); o[3] = f2b_rne(a.w);
    o[4] = f2b_rne(b.x); o[5] = f2b_rne(b.y); o[6] = f2b_rne(b.z); o[7] = f2b_rne(b.w);
    *(ushort8*)(dst + i) = o;
  }
}

// ---------------- mask statistics (single launch, 1024 threads) ----------------
__global__ __launch_bounds__(1024) void mask_stats(
    const int* __restrict__ am, float* __restrict__ wsum, float* __restrict__ svalid,
    float* __restrict__ cnt2, float* __restrict__ secv, float* __restrict__ cnt3) {
  int tid = threadIdx.x;
  int s = 0;
  const int* p = am + (size_t)tid * 64;
  for (int w = 0; w < 64; ++w) s += p[w];
  wsum[tid] = (float)s;
  float sv = s > 0 ? 1.f : 0.f;
  svalid[tid] = sv;
  __shared__ float sva[1024];
  sva[tid] = sv;
  __syncthreads();
  if (tid < 64) {
    float c = 0.f;
    for (int u = 0; u < 16; ++u) c += sva[tid * 16 + u];
    cnt2[tid] = c;
    secv[tid] = c > 0.f ? 1.f : 0.f;
  }
  __syncthreads();
  if (tid < 64) sva[tid] = secv[tid];
  __syncthreads();
  if (tid < 8) {
    float c = 0.f;
    for (int s2 = 0; s2 < 8; ++s2) c += sva[tid * 8 + s2];
    cnt3[tid] = c;
  }
}

// ---------------- Q,K projection: BK=64 double-buffered bf16 MFMA GEMM ----------
// (R8-proven inner loop; head-blocked output with hoisted epilogue addressing.)
// 256x256 tile, BK=64, 8 waves (2Mx4N, per-wave 128x64), 2 LDS slots (128 KiB).
//   qk_blk[sent][head][q|k][kc(6)][row 64][col 32] bf16
__global__ __launch_bounds__(512, 2) void gemm8(
    const unsigned short* __restrict__ A, const unsigned short* __restrict__ B,
    const float* __restrict__ bias, unsigned short* __restrict__ C,
    int M, int N, int K) {
  __shared__ unsigned short lds[2][32768];  // [slot][A:256x64 | B:256x64]
  const int tid = threadIdx.x;
  const int w = tid >> 6;
  const int lane = tid & 63;
  const int nbx = N / 256;
  const int cpx = gridDim.x >> 3;
  const int bid = blockIdx.x;
  const int swz = (bid & 7) * cpx + (bid >> 3);
  const int m0 = (swz / nbx) * 256;
  const int n0 = (swz % nbx) * 256;
  const int wr = w >> 2, wc = w & 3;  // 2x4 wave grid; per-wave C: 128x64
  const int fr = lane & 15;
  const int g = lane >> 4;
  const int NT64 = K / 64;
  f32x4 acc[8][4] = {};

  // staging source coords: chunk S -> row = S>>3, colchunk = (S&7)^(row&7)
  int srow[4], scol[4];
#pragma unroll
  for (int q = 0; q < 4; ++q) {
    int S = q * 512 + tid;
    srow[q] = S >> 3;
    scol[q] = ((S & 7) ^ (srow[q] & 7)) * 8;
  }
  auto stageA = [&](int t, int slot) {
    const int kt = t * 64;
#pragma unroll
    for (int q = 0; q < 4; ++q)
      gload_lds16(A + (size_t)(m0 + srow[q]) * K + kt + scol[q],
                  &lds[slot][(q * 512 + w * 64) * 8]);
  };
  auto stageB = [&](int t, int slot) {
    const int kt = t * 64;
#pragma unroll
    for (int q = 0; q < 4; ++q)
      gload_lds16(B + (size_t)(n0 + srow[q]) * K + kt + scol[q],
                  &lds[slot][16384 + (q * 512 + w * 64) * 8]);
  };
  // fragment read offsets (ushort units), chunk-in-row = ks*4+g, XOR row&7
  int aoff[2][8], boff[2][4];
#pragma unroll
  for (int ks = 0; ks < 2; ++ks) {
#pragma unroll
    for (int i = 0; i < 8; ++i) {
      int r = wr * 128 + i * 16 + fr;
      aoff[ks][i] = (r * 8 + ((ks * 4 + g) ^ (r & 7))) * 8;
    }
#pragma unroll
    for (int j = 0; j < 4; ++j) {
      int r = wc * 64 + j * 16 + fr;
      boff[ks][j] = 16384 + (r * 8 + ((ks * 4 + g) ^ (r & 7))) * 8;
    }
  }

  // prologue: stage tile 0 into slot 0, drain, barrier
  stageA(0, 0);
  stageB(0, 0);
  asm volatile("s_waitcnt vmcnt(0)" ::: "memory");
  __builtin_amdgcn_sched_barrier(0);
  __builtin_amdgcn_s_barrier();
  __builtin_amdgcn_sched_barrier(0);

  int slot = 0;
  for (int t = 0; t < NT64; ++t) {
    const unsigned short* ls = lds[slot];
    if (t + 1 < NT64) stageA(t + 1, slot ^ 1);  // issue early (hide under ks0)
    short8 av[8], bv[4];
    // ---- ks = 0 cluster
#pragma unroll
    for (int i = 0; i < 8; ++i) av[i] = *(const short8*)(ls + aoff[0][i]);
#pragma unroll
    for (int j = 0; j < 4; ++j) bv[j] = *(const short8*)(ls + boff[0][j]);
    __builtin_amdgcn_s_setprio(1);
#pragma unroll
    for (int i = 0; i < 8; ++i)
#pragma unroll
      for (int j = 0; j < 4; ++j)
        acc[i][j] = __builtin_amdgcn_mfma_f32_16x16x32_bf16(av[i], bv[j], acc[i][j], 0, 0, 0);
    __builtin_amdgcn_s_setprio(0);
    if (t + 1 < NT64) stageB(t + 1, slot ^ 1);  // issue mid-tile
    // ---- ks = 1 cluster
#pragma unroll
    for (int i = 0; i < 8; ++i) av[i] = *(const short8*)(ls + aoff[1][i]);
#pragma unroll
    for (int j = 0; j < 4; ++j) bv[j] = *(const short8*)(ls + boff[1][j]);
    __builtin_amdgcn_s_setprio(1);
#pragma unroll
    for (int i = 0; i < 8; ++i)
#pragma unroll
      for (int j = 0; j < 4; ++j)
        acc[i][j] = __builtin_amdgcn_mfma_f32_16x16x32_bf16(av[i], bv[j], acc[i][j], 0, 0, 0);
    __builtin_amdgcn_s_setprio(0);
    // boundary: tile t+1 must be fully landed before next iteration reads it
    asm volatile("s_waitcnt vmcnt(0)" ::: "memory");
    __builtin_amdgcn_sched_barrier(0);
    __builtin_amdgcn_s_barrier();
    __builtin_amdgcn_sched_barrier(0);
    slot ^= 1;
  }

  // epilogue: bias + bf16 store into head-blocked layout.
  // Column-derived address math hoisted per j (constant over i,r); sentence/row
  // base per i (4-row group never crosses a 64-row sentence boundary).
  const int cl = lane & 15;
  const int rg = (lane >> 4) * 4;
#pragma unroll
  for (int j = 0; j < 4; ++j) {
    const int col = n0 + wc * 64 + j * 16 + cl;
    const float bvv = bias[col];
    const int qkf = col >= 768;
    const int within = col - qkf * 768;
    const int hh = within / 192;
    const int rem = within - hh * 192;
    const int kc = rem >> 5;
    const int cw = rem & 31;
    const size_t colbase = ((size_t)(hh * 2 + qkf) * 6 + kc) * 2048 + cw;
#pragma unroll
    for (int i = 0; i < 8; ++i) {
      const int mrow0 = m0 + wr * 128 + i * 16 + rg;
      const size_t sbase = (size_t)(mrow0 >> 6) * 98304 + colbase;
      const int row0 = mrow0 & 63;
#pragma unroll
      for (int r = 0; r < 4; ++r)
        C[sbase + (size_t)(row0 + r) * 32] = f2b_rne(acc[i][j][r] + bvv);
    }
  }
}

// ---------------- word-level attention from head-blocked Q,K (bf16) ----------------
// qk_blk[sent][head][q|k][kc][64][32]: each short8 fragment load is a contiguous
// 1 KB wave transaction (fully coalesced).
__global__ __launch_bounds__(256) void attn_qk(
    const unsigned short* __restrict__ qk, const unsigned short* __restrict__ xbf,
    const int* __restrict__ am, const float* __restrict__ wsum,
    unsigned short* __restrict__ xbarbf) {
  __shared__ float abar_all[4][64];
  __shared__ float msk[64];
  const int n = blockIdx.x;
  const int tid = threadIdx.x;
  const int h = tid >> 6;  // wave = head
  const int lane = tid & 63;
  if (tid < 64) msk[tid] = (am[(size_t)n * 64 + tid] > 0) ? 1.f : 0.f;
  __syncthreads();
  const int fr = lane & 15;
  const int fk = (lane >> 4) * 8;
  const unsigned short* Sg = qk + (size_t)n * 98304 + (size_t)h * 24576;  // head base
  const unsigned short* Kb = Sg + 12288;                                   // k half
  f32x4 acc[4][4] = {};
#pragma unroll
  for (int ks = 0; ks < 6; ++ks) {
    short8 aq[4], bk[4];
#pragma unroll
    for (int i = 0; i < 4; ++i)
      aq[i] = *(const short8*)(Sg + ks * 2048 + (i * 16 + fr) * 32 + fk);
#pragma unroll
    for (int j = 0; j < 4; ++j)
      bk[j] = *(const short8*)(Kb + ks * 2048 + (j * 16 + fr) * 32 + fk);
#pragma unroll
    for (int i = 0; i < 4; ++i)
#pragma unroll
      for (int j = 0; j < 4; ++j)
        acc[i][j] = __builtin_amdgcn_mfma_f32_16x16x32_bf16(aq[i], bk[j], acc[i][j], 0, 0, 0);
  }
  const float den = wsum[n] + 1e-10f;
  const float scale = 0.07216878364870323f;  // 1/sqrt(192)
  float mcol[4];
#pragma unroll
  for (int j = 0; j < 4; ++j) mcol[j] = msk[j * 16 + fr];
  float colsum[4] = {0.f, 0.f, 0.f, 0.f};
#pragma unroll
  for (int i = 0; i < 4; ++i) {
#pragma unroll
    for (int r = 0; r < 4; ++r) {
      float s[4];
      float mx = -1e30f;
#pragma unroll
      for (int j = 0; j < 4; ++j) {
        float v = mcol[j] > 0.f ? acc[i][j][r] * scale : -1e9f;
        s[j] = v;
        mx = fmaxf(mx, v);
      }
      mx = fmaxf(mx, __shfl_xor(mx, 1));
      mx = fmaxf(mx, __shfl_xor(mx, 2));
      mx = fmaxf(mx, __shfl_xor(mx, 4));
      mx = fmaxf(mx, __shfl_xor(mx, 8));
      float sum = 0.f;
#pragma unroll
      for (int j = 0; j < 4; ++j) { s[j] = expf(s[j] - mx); sum += s[j]; }
      sum += __shfl_xor(sum, 1);
      sum += __shfl_xor(sum, 2);
      sum += __shfl_xor(sum, 4);
      sum += __shfl_xor(sum, 8);
      float wrow = msk[i * 16 + (lane >> 4) * 4 + r] / den;
      float f = wrow / sum;
#pragma unroll
      for (int j = 0; j < 4; ++j) colsum[j] += s[j] * f;
    }
  }
#pragma unroll
  for (int j = 0; j < 4; ++j) {
    float cs = colsum[j];
    cs += __shfl_xor(cs, 16);
    cs += __shfl_xor(cs, 32);
    if (lane < 16) abar_all[h][j * 16 + lane] = cs;
  }
  __syncthreads();
  const unsigned short* xg = xbf + (size_t)n * 64 * 768;
  float a4[4][3] = {};
  for (int m = 0; m < 64; ++m) {
    float ab0 = abar_all[0][m], ab1 = abar_all[1][m];
    float ab2 = abar_all[2][m], ab3 = abar_all[3][m];
#pragma unroll
    for (int u = 0; u < 3; ++u) {
      float x = b2f(xg[(size_t)m * 768 + u * 256 + tid]);
      a4[0][u] += ab0 * x;
      a4[1][u] += ab1 * x;
      a4[2][u] += ab2 * x;
      a4[3][u] += ab3 * x;
    }
  }
#pragma unroll
  for (int hh = 0; hh < 4; ++hh)
#pragma unroll
    for (int u = 0; u < 3; ++u)
      xbarbf[((size_t)hh * 1024 + n) * 768 + u * 256 + tid] = f2b_rne(a4[hh][u]);
}

// ---------------- bf16 MFMA GEMM, 128x64 tile, grid.z-batched, fp32/bf16 out ------
__global__ __launch_bounds__(256) void gemm_bf16_64(
    const unsigned short* __restrict__ A, const unsigned short* __restrict__ B,
    const float* __restrict__ bias, const float* __restrict__ cnt,
    float* __restrict__ C, unsigned short* __restrict__ Cb,
    int K, int ldc, size_t Az, size_t Bz, int colz) {
  __shared__ unsigned short smA[128 * 32];
  __shared__ unsigned short smB[64 * 32];
  const int tid = threadIdx.x;
  const int wid = tid >> 6;
  const int lane = tid & 63;
  const int za = blockIdx.z;
  A += (size_t)za * Az;
  B += (size_t)za * Bz;
  const int m0 = blockIdx.y * 128;
  const int nb = blockIdx.x * 64;
  const int wr = wid >> 1, wc = wid & 1;
  const int srow = lane >> 2;
  const int scol = (lane & 3) * 8;
  const int fr = lane & 15;
  const int fk = (lane >> 4) * 8;
  f32x4 acc[4][2] = {};
  for (int k0 = 0; k0 < K; k0 += 32) {
#pragma unroll
    for (int t = 0; t < 2; ++t) {
      const int r0 = wid * 32 + t * 16;
      gload_lds16(A + (size_t)(m0 + r0 + srow) * K + k0 + scol, &smA[r0 * 32]);
    }
    gload_lds16(B + (size_t)(nb + wid * 16 + srow) * K + k0 + scol, &smB[wid * 16 * 32]);
    __syncthreads();
    short8 af[4], bfr[2];
#pragma unroll
    for (int i = 0; i < 4; ++i)
      af[i] = *(const short8*)&smA[(wr * 64 + i * 16 + fr) * 32 + fk];
#pragma unroll
    for (int j = 0; j < 2; ++j)
      bfr[j] = *(const short8*)&smB[(wc * 32 + j * 16 + fr) * 32 + fk];
#pragma unroll
    for (int i = 0; i < 4; ++i)
#pragma unroll
      for (int j = 0; j < 2; ++j)
        acc[i][j] = __builtin_amdgcn_mfma_f32_16x16x32_bf16(af[i], bfr[j], acc[i][j], 0, 0, 0);
    __syncthreads();
  }
  const int cl = lane & 15;
  const int rg = (lane >> 4) * 4;
#pragma unroll
  for (int i = 0; i < 4; ++i) {
    const int mrow0 = m0 + wr * 64 + i * 16 + rg;
#pragma unroll
    for (int j = 0; j < 2; ++j) {
      const int gc = za * colz + nb + wc * 32 + j * 16 + cl;
      const float bv = bias[gc];
#pragma unroll
      for (int r = 0; r < 4; ++r) {
        const int m = mrow0 + r;
        float sf = 1.f;
        if (cnt) { float c = cnt[m]; sf = c / (c + 1e-10f); }
        float v = acc[i][j][r] + bv * sf;
        if (Cb) Cb[(size_t)m * ldc + gc] = f2b_rne(v);
        else C[(size_t)m * ldc + gc] = v;
      }
    }
  }
}

// ---------------- fp32 GEMM: out[m,n] = sum_k X[m*lda+k]*W[n,k] + bias[n]*sfac(m) ------
#define BM 64
#define BN 64
#define BK 16
__global__ __launch_bounds__(256) void gemm_nt(
    const float* __restrict__ X, const float* __restrict__ W,
    const float* __restrict__ bias, const float* __restrict__ cnt,
    float* __restrict__ out, int M, int N, int K, int lda, int ldc) {
  __shared__ float As[BK][BM + 4];
  __shared__ float Bs[BK][BN + 4];
  const int tid = threadIdx.x;
  const int m0 = blockIdx.y * BM;
  const int n0 = blockIdx.x * BN;
  const int tx = tid & 15, ty = tid >> 4;
  const int lr = tid >> 2;
  const int lc = (tid & 3) * 4;
  float acc[4][4];
#pragma unroll
  for (int i = 0; i < 4; ++i)
#pragma unroll
    for (int j = 0; j < 4; ++j) acc[i][j] = 0.f;
  for (int k0 = 0; k0 < K; k0 += BK) {
    float4 xa = make_float4(0.f, 0.f, 0.f, 0.f);
    if (m0 + lr < M) xa = *(const float4*)(X + (size_t)(m0 + lr) * lda + k0 + lc);
    float4 wb = *(const float4*)(W + (size_t)(n0 + lr) * K + k0 + lc);
    As[lc + 0][lr] = xa.x; As[lc + 1][lr] = xa.y; As[lc + 2][lr] = xa.z; As[lc + 3][lr] = xa.w;
    Bs[lc + 0][lr] = wb.x; Bs[lc + 1][lr] = wb.y; Bs[lc + 2][lr] = wb.z; Bs[lc + 3][lr] = wb.w;
    __syncthreads();
#pragma unroll
    for (int kk = 0; kk < BK; ++kk) {
      float4 av = *(const float4*)&As[kk][ty * 4];
      float4 bv = *(const float4*)&Bs[kk][tx * 4];
      float a4[4] = {av.x, av.y, av.z, av.w};
      float b4[4] = {bv.x, bv.y, bv.z, bv.w};
#pragma unroll
      for (int i = 0; i < 4; ++i)
#pragma unroll
        for (int j = 0; j < 4; ++j) acc[i][j] += a4[i] * b4[j];
    }
    __syncthreads();
  }
#pragma unroll
  for (int i = 0; i < 4; ++i) {
    int m = m0 + ty * 4 + i;
    if (m < M) {
      float sf = 1.f;
      if (cnt) { float c = cnt[m]; sf = c / (c + 1e-10f); }
      float4 o;
      o.x = acc[i][0] + bias[n0 + tx * 4 + 0] * sf;
      o.y = acc[i][1] + bias[n0 + tx * 4 + 1] * sf;
      o.z = acc[i][2] + bias[n0 + tx * 4 + 2] * sf;
      o.w = acc[i][3] + bias[n0 + tx * 4 + 3] * sf;
      *(float4*)(out + (size_t)m * ldc + n0 + tx * 4) = o;
    }
  }
}

// ---------------- small attention (L=16 or 8), pooled output, fp32 or bf16 qkv ----
template <class T>
__global__ __launch_bounds__(256) void small_attn(
    const T* __restrict__ qkv, const float* __restrict__ maskv,
    const float* __restrict__ cnt, float* __restrict__ obar, int L) {
  const int n = blockIdx.x;
  const int h = blockIdx.y;
  const int tid = threadIdx.x;
  __shared__ float red[16][17];
  __shared__ float abar[16];
  const T* qb = qkv + (size_t)n * L * E3 + h * 192;
  const T* kb = qb + EDIM;
  const T* vb = qb + 2 * EDIM;
  const float scale = 0.07216878364870323f;
  if (tid < L * L) {
    int l = tid / L, m = tid % L;
    float s = 0.f;
    for (int dd = 0; dd < 192; ++dd) s += ldv(qb[(size_t)l * E3 + dd]) * ldv(kb[(size_t)m * E3 + dd]);
    s = (maskv[n * L + m] > 0.f) ? s * scale : -1e9f;
    float mx = s;
    for (int off = L >> 1; off > 0; off >>= 1) mx = fmaxf(mx, __shfl_xor(mx, off));
    float p = expf(s - mx);
    float sum = p;
    for (int off = L >> 1; off > 0; off >>= 1) sum += __shfl_xor(sum, off);
    float dn = cnt[n] + 1e-10f;
    float wl = (maskv[n * L + l] > 0.f) ? (1.f / dn) : 0.f;
    red[l][m] = p / sum * wl;
  }
  __syncthreads();
  if (tid < L) {
    float s = 0.f;
    for (int l2 = 0; l2 < L; ++l2) s += red[l2][tid];
    abar[tid] = s;
  }
  __syncthreads();
  if (tid < 192) {
    float acc = 0.f;
    for (int m = 0; m < L; ++m) acc += abar[m] * ldv(vb[(size_t)m * E3 + tid]);
    obar[(size_t)n * EDIM + h * 192 + tid] = acc;
  }
}

// ---------------- fusion head: [8,768] doc -> [8,3] ----------------
__global__ __launch_bounds__(256) void head_kernel(
    const float* __restrict__ doc, const float* __restrict__ hand,
    const float* __restrict__ bp_w, const float* __restrict__ bp_b,
    const float* __restrict__ hp_w, const float* __restrict__ hp_b,
    const float* __restrict__ gate_w, const float* __restrict__ gate_b,
    const float* __restrict__ fg, const float* __restrict__ fbv,
    const float* __restrict__ fc1_w, const float* __restrict__ fc1_b,
    const float* __restrict__ g1, const float* __restrict__ b1,
    const float* __restrict__ fc2_w, const float* __restrict__ fc2_b,
    float* __restrict__ out) {
  int b = blockIdx.x, tid = threadIdx.x;
  __shared__ float bp[256], hp[256], fz[256], hz[128];
  const float* dr = doc + (size_t)b * 768;
  float acc = bp_b[tid];
  for (int k = 0; k < 768; ++k) acc += dr[k] * bp_w[(size_t)tid * 768 + k];
  bp[tid] = acc;
  const float* hr = hand + b * 20;
  float acc2 = hp_b[tid];
  for (int k = 0; k < 20; ++k) acc2 += hr[k] * hp_w[tid * 20 + k];
  hp[tid] = acc2;
  __syncthreads();
  float g = gate_b[tid];
  for (int k = 0; k < 256; ++k) g += bp[k] * gate_w[tid * 512 + k];
  for (int k = 0; k < 256; ++k) g += hp[k] * gate_w[tid * 512 + 256 + k];
  g = 1.f / (1.f + expf(-g));
  float fu = g * bp[tid] + (1.f - g) * hp[tid];
  fz[tid] = fu;
  __syncthreads();
  float mu = 0.f;
  for (int k = 0; k < 256; ++k) mu += fz[k];
  mu /= 256.f;
  float va = 0.f;
  for (int k = 0; k < 256; ++k) { float d = fz[k] - mu; va += d * d; }
  va /= 256.f;
  float fl = (fu - mu) / sqrtf(va + 1e-5f) * fg[tid] + fbv[tid];
  __syncthreads();
  fz[tid] = fl;
  __syncthreads();
  if (tid < 128) {
    float a = fc1_b[tid];
    for (int k = 0; k < 256; ++k) a += fz[k] * fc1_w[tid * 256 + k];
    hz[tid] = fmaxf(a, 0.f);
  }
  __syncthreads();
  float mu2 = 0.f;
  for (int k = 0; k < 128; ++k) mu2 += hz[k];
  mu2 /= 128.f;
  float va2 = 0.f;
  for (int k = 0; k < 128; ++k) { float d = hz[k] - mu2; va2 += d * d; }
  va2 /= 128.f;
  __syncthreads();
  if (tid < 128) hz[tid] = (hz[tid] - mu2) / sqrtf(va2 + 1e-5f) * g1[tid] + b1[tid];
  __syncthreads();
  if (tid < 3) {
    float o = fc2_b[tid];
    for (int k = 0; k < 128; ++k) o += hz[k] * fc2_w[tid * 128 + k];
    out[b * 3 + tid] = o;
  }
}

extern "C" void kernel_launch(void* const* d_in, const int* in_sizes, int n_in,
                              void* d_out, int out_size, void* d_ws, size_t ws_size,
                              hipStream_t stream) {
  const float* we      = (const float*)d_in[0];
  const int*   am      = (const int*)d_in[1];
  const float* hand    = (const float*)d_in[2];
  const float* w_w_in  = (const float*)d_in[3];
  const float* w_b_in  = (const float*)d_in[4];
  const float* w_w_out = (const float*)d_in[5];
  const float* w_b_out = (const float*)d_in[6];
  const float* s_w_in  = (const float*)d_in[7];
  const float* s_b_in  = (const float*)d_in[8];
  const float* s_w_out = (const float*)d_in[9];
  const float* s_b_out = (const float*)d_in[10];
  const float* c_w_in  = (const float*)d_in[11];
  const float* c_b_in  = (const float*)d_in[12];
  const float* c_w_out = (const float*)d_in[13];
  const float* c_b_out = (const float*)d_in[14];
  const float* bp_w = (const float*)d_in[15];
  const float* bp_b = (const float*)d_in[16];
  const float* hp_w = (const float*)d_in[17];
  const float* hp_b = (const float*)d_in[18];
  // d_in[19..22] = fa_* (cross-attention) — output unused by the reference, skipped.
  const float* gate_w = (const float*)d_in[23];
  const float* gate_b = (const float*)d_in[24];
  const float* fus_g  = (const float*)d_in[25];
  const float* fus_b  = (const float*)d_in[26];
  const float* fc1_w  = (const float*)d_in[27];
  const float* fc1_b  = (const float*)d_in[28];
  const float* ln1_g  = (const float*)d_in[29];
  const float* ln1_b  = (const float*)d_in[30];
  const float* fc2_w  = (const float*)d_in[31];
  const float* fc2_b  = (const float*)d_in[32];
  float* out = (float*)d_out;

  // big buffers at the bottom of the workspace
  unsigned short* qk  = (unsigned short*)d_ws;                      // head-blocked, 201 MB
  unsigned short* xbf = qk + (size_t)65536 * 1536;                  // [65536][768]  bf16

  // small buffers carved from the top
  char* end = (char*)d_ws + ws_size;
  auto carveb = [&](size_t bytes) {
    size_t b = (bytes + 255) & ~(size_t)255;
    end -= b;
    return (void*)end;
  };
  unsigned short* xbarbf  = (unsigned short*)carveb((size_t)4 * 1024 * 768 * 2);
  unsigned short* obarbf  = (unsigned short*)carveb((size_t)1024 * 768 * 2);
  unsigned short* sentbf  = (unsigned short*)carveb((size_t)1024 * 768 * 2);
  unsigned short* qkv2bf  = (unsigned short*)carveb((size_t)1024 * 2304 * 2);
  float* obar2  = (float*)carveb(64 * 768 * 4);
  float* sec    = (float*)carveb(64 * 768 * 4);
  float* qkv3   = (float*)carveb(64 * 2304 * 4);
  float* obar3  = (float*)carveb(8 * 768 * 4);
  float* doc    = (float*)carveb(8 * 768 * 4);
  float* wsum   = (float*)carveb(1024 * 4);
  float* svalid = (float*)carveb(1024 * 4);
  float* cnt2   = (float*)carveb(64 * 4);
  float* secv   = (float*)carveb(64 * 4);
  float* cnt3   = (float*)carveb(8 * 4);
  unsigned short* wbf_in = (unsigned short*)carveb((size_t)2304 * 768 * 2);
  unsigned short* wobf   = (unsigned short*)carveb((size_t)768 * 768 * 2);
  unsigned short* wsbf   = (unsigned short*)carveb((size_t)2304 * 768 * 2);

  // prep: weights -> bf16 (single launch), mask stats (single launch)
  f2bf3<<<2048, 256, 0, stream>>>(w_w_in, wbf_in, (size_t)2304 * 768,
                                  w_w_out, wobf, (size_t)768 * 768,
                                  s_w_in, wsbf, (size_t)2304 * 768);
  mask_stats<<<1, 1024, 0, stream>>>(am, wsum, svalid, cnt2, secv, cnt3);

  // word level
  f2bf<<<2048, 256, 0, stream>>>(we, xbf, (size_t)65536 * 768);
  gemm8<<<(65536 / 256) * (1536 / 256), 512, 0, stream>>>(xbf, wbf_in, w_b_in, qk,
                                                          65536, 1536, 768);
  attn_qk<<<1024, 256, 0, stream>>>(qk, xbf, am, wsum, xbarbf);
  // V-projection (batched per head): obar[n, h*192+c] = xbar[h][n,:] @ Wv_h^T + bv*sfac
  gemm_bf16_64<<<dim3(3, 8, 4), 256, 0, stream>>>(
      xbarbf, wbf_in + (size_t)1536 * 768, w_b_in + 1536, wsum, nullptr, obarbf,
      768, 768, (size_t)1024 * 768, (size_t)192 * 768, 192);
  // sent = obar @ w_out^T + b_out * sfac
  gemm_bf16_64<<<dim3(12, 8, 1), 256, 0, stream>>>(
      obarbf, wobf, w_b_out, wsum, nullptr, sentbf, 768, 768, 0, 0, 0);
  // sentence level QKV
  gemm_bf16_64<<<dim3(36, 8, 1), 256, 0, stream>>>(
      sentbf, wsbf, s_b_in, nullptr, nullptr, qkv2bf, 768, 2304, 0, 0, 0);
  small_attn<<<dim3(64, 4), 256, 0, stream>>>(qkv2bf, svalid, cnt2, obar2, 16);
  gemm_nt<<<dim3(12, 1), 256, 0, stream>>>(obar2, s_w_out, s_b_out, cnt2, sec,
                                           64, 768, 768, 768, 768);
  // section level
  gemm_nt<<<dim3(36, 1), 256, 0, stream>>>(sec, c_w_in, c_b_in, nullptr, qkv3,
                                           64, 2304, 768, 768, 2304);
  small_attn<<<dim3(8, 4), 256, 0, stream>>>(qkv3, secv, cnt3, obar3, 8);
  gemm_nt<<<dim3(12, 1), 256, 0, stream>>>(obar3, c_w_out, c_b_out, cnt3, doc,
                                           8, 768, 768, 768, 768);
  // fusion head
  head_kernel<<<8, 256, 0, stream>>>(doc, hand, bp_w, bp_b, hp_w, hp_b, gate_w, gate_b,
                                     fus_g, fus_b, fc1_w, fc1_b, ln1_g, ln1_b, fc2_w, fc2_b, out);
}